// Round 8
// baseline (404.262 us; speedup 1.0000x reference)
//
#include <hip/hip_runtime.h>
#include <math.h>

#define NCLS 19
#define HW   (512*1024)          // 524288
#define HW4  (HW/4)              // 131072 float4 per channel
#define CHW  (NCLS*HW)
#define TPIX (2*HW)              // 1048576
#define NB   8192
#define CAND_MAX 4096
#define SUBB 1024                // K4 sub-bins within one conf bin
#define WCAP 1024                // K4 final-candidate capacity

// ---- workspace layout (bytes) ----
#define WS_HIST   0                          // NCLS*NB*4 = 622592
#define WS_CANDC  622592                     // NCLS*4 candidate counters
#define WS_ACCUM  622720                     // [0]=sum_loss f32, [1]=cnt_mask u32, [2]=cnt_solid u32
#define WS_TICKET 622736                     // u32 block-completion ticket for fused K5 output
#define WS_ZERO   622848                     // memset range [0, WS_ZERO)
#define WS_SEL    622848                     // NCLS * {int bin, int rank}
#define WS_NEWTH  623360                     // NCLS*4
#define WS_CONF   623616                     // TPIX*4
#define WS_LOSS   4817920                    // TPIX*4
#define WS_LABEL  9012224                    // TPIX*1
#define WS_CAND   10060800                   // NCLS*CAND_MAX*4 -> end 10372096

// ---------------- K1: channel-OUTER streaming softmax ----------------
// R1-R6 invariance explained: every variant had each wave touching 38 distinct
// 2MB-strided pages per pixel-visit (38 > ~32 UTCL1 entries -> translation
// thrash; miss handling serialized per CU ~= 100+ us regardless of request
// shaping — which is why MLP/bursts never helped). Fix the PAGE-VISIT COUNT:
// loop channels outer, online-softmax state in registers (7 regs x 4 px),
// block dwells on one 4KB-aligned window per channel (~38 page-touches/block
// instead of 38/wave-iteration). 1-deep pipeline: load c+1 while computing c.
__global__ __launch_bounds__(256)
void k1_pixel(const float4* __restrict__ lb_t, const float4* __restrict__ la_t,
              float4* __restrict__ conf_o, float4* __restrict__ loss_o,
              unsigned int* __restrict__ label_o, unsigned int* __restrict__ hist)
{
    int g  = blockIdx.x * 256 + threadIdx.x;      // float4-group id, [0, TPIX/4)
    int n  = g >> 17;                             // g / HW4
    int r4 = g & (HW4 - 1);
    const float4* lb = lb_t + (size_t)n * (CHW / 4) + r4;
    const float4* la = la_t + (size_t)n * (CHW / 4) + r4;

    float mb[4], zb[4], dot[4], alab[4], ma[4], za[4];
    int lab[4];

    // channel 0: init state
    {
        float4 b4 = lb[0];
        float4 a4 = la[0];
        float bb[4] = {b4.x, b4.y, b4.z, b4.w};
        float aa[4] = {a4.x, a4.y, a4.z, a4.w};
#pragma unroll
        for (int i = 0; i < 4; ++i) {
            mb[i] = bb[i]; zb[i] = 1.0f; dot[i] = aa[i];
            lab[i] = 0; alab[i] = aa[i]; ma[i] = aa[i]; za[i] = 1.0f;
        }
    }

    // pipeline: cur holds channel c's data; next load issued before compute
    float4 cb = lb[HW4];          // channel 1
    float4 ca = la[HW4];
#pragma unroll 1
    for (int c = 1; c < NCLS; ++c) {
        float4 nb, na;
        if (c + 1 < NCLS) {                        // issue c+1 loads (independent)
            nb = lb[(size_t)(c + 1) * HW4];
            na = la[(size_t)(c + 1) * HW4];
        }
        float bb[4] = {cb.x, cb.y, cb.z, cb.w};
        float aa[4] = {ca.x, ca.y, ca.z, ca.w};
#pragma unroll
        for (int i = 0; i < 4; ++i) {
            // before-softmax online (max, Z, dot(pb_unnorm, la))
            float mn = fmaxf(mb[i], bb[i]);
            float eo = __expf(mb[i] - mn);
            float en = __expf(bb[i] - mn);
            zb[i]  = zb[i] * eo + en;
            dot[i] = dot[i] * eo + en * aa[i];
            bool upd = bb[i] > mb[i];              // first-max-wins (strict >)
            lab[i]  = upd ? c : lab[i];
            alab[i] = upd ? aa[i] : alab[i];
            mb[i] = mn;
            // after-softmax online (max, Z)
            float mna = fmaxf(ma[i], aa[i]);
            za[i] = za[i] * __expf(ma[i] - mna) + __expf(aa[i] - mna);
            ma[i] = mna;
        }
        cb = nb; ca = na;
    }

    float cf[4], ls[4];
#pragma unroll
    for (int i = 0; i < 4; ++i) {
        cf[i] = 1.0f / zb[i];                      // max softmax prob
        float pa_lab = __expf(alab[i] - ma[i]) / za[i];
        ls[i] = (1.0f - pa_lab) * (ma[i] + __logf(za[i]) - dot[i] / zb[i]);
    }

    conf_o[g] = make_float4(cf[0], cf[1], cf[2], cf[3]);
    loss_o[g] = make_float4(ls[0], ls[1], ls[2], ls[3]);
    label_o[g] = (unsigned)lab[0] | ((unsigned)lab[1] << 8) |
                 ((unsigned)lab[2] << 16) | ((unsigned)lab[3] << 24);

#pragma unroll
    for (int i = 0; i < 4; ++i) {
        int bin = (int)(cf[i] * (float)NB);
        bin = bin < (NB - 1) ? bin : (NB - 1);
        atomicAdd(&hist[lab[i] * NB + bin], 1u);
    }
}

// ---------------- K2: per-class rank -> (bin, rank-in-bin) ----------------
__global__ __launch_bounds__(256)
void k2_select(const unsigned int* __restrict__ hist, const float* __restrict__ cls_thresh,
               int* __restrict__ sel, unsigned int* __restrict__ cand_cnt,
               float* __restrict__ cand)
{
    int c = blockIdx.x;
    int t = threadIdx.x;
    float thr = cls_thresh[c];
    int thr_bin = (int)(thr * (float)NB); thr_bin = thr_bin < (NB-1) ? thr_bin : (NB-1);

    __shared__ unsigned hh[NB];                    // 32 KB, coalesced staging
    for (int i = t; i < NB; i += 256) hh[i] = hist[c * NB + i];
    __syncthreads();

    // thread t owns DESCENDING chunk of 32 bins: [NB-(t+1)*32, NB-t*32)
    int base = NB - (t + 1) * 32;
    unsigned s = 0;
    for (int i = 0; i < 32; ++i) {
        unsigned h = hh[base + i];
        if (base + i == thr_bin) h += 1u;          // extended multiset: append thr
        s += h;
    }
    __shared__ unsigned sc[256];
    sc[t] = s;
    __syncthreads();
    for (int off = 1; off < 256; off <<= 1) {
        unsigned vt = sc[t];
        unsigned vp = (t >= off) ? sc[t - off] : 0u;
        __syncthreads();
        sc[t] = vt + vp;
        __syncthreads();
    }
    unsigned total_ext = sc[255];                  // count_c + 1
    unsigned cnt = total_ext - 1u;
    int idx = (int)floorf((float)(cnt + 1u) * 0.2f * powf(thr, 8.0f));

    unsigned above = sc[t] - s;                    // strictly above this chunk
    if ((unsigned)idx >= above && (unsigned)idx < above + s) {
        unsigned cum = above;
        int B = thr_bin, r = 0;
        for (int i = 31; i >= 0; --i) {
            int bi = base + i;
            unsigned h = hh[bi];
            if (bi == thr_bin) h += 1u;
            if ((unsigned)idx < cum + h) { B = bi; r = (int)((unsigned)idx - cum); break; }
            cum += h;
        }
        sel[2 * c]     = B;
        sel[2 * c + 1] = r;
        if (B == thr_bin) {                        // the appended thr is a candidate
            unsigned pos = atomicAdd(&cand_cnt[c], 1u);
            if (pos < CAND_MAX) cand[c * CAND_MAX + pos] = thr;
        }
    }
}

// ---------------- K3: gather candidates in selection bin (4 px/thread) ----------------
__global__ __launch_bounds__(256)
void k3_gather(const float4* __restrict__ conf, const uchar4* __restrict__ label,
               const int* __restrict__ sel, unsigned int* __restrict__ cand_cnt,
               float* __restrict__ cand)
{
    int g = blockIdx.x * 256 + threadIdx.x;
    float4 c4 = conf[g];
    uchar4 l4 = label[g];
    float cf[4] = {c4.x, c4.y, c4.z, c4.w};
    int   lb[4] = {l4.x, l4.y, l4.z, l4.w};
#pragma unroll
    for (int i = 0; i < 4; ++i) {
        int bin = (int)(cf[i] * (float)NB);
        bin = bin < (NB - 1) ? bin : (NB - 1);
        if (bin == sel[2 * lb[i]]) {
            unsigned pos = atomicAdd(&cand_cnt[lb[i]], 1u);
            if (pos < CAND_MAX) cand[lb[i] * CAND_MAX + pos] = cf[i];
        }
    }
}

// ---------------- K4: rank among candidates via sub-bin histogram, O(m) ----------------
__global__ __launch_bounds__(256)
void k4_thresh(const int* __restrict__ sel, const unsigned int* __restrict__ cand_cnt,
               const float* __restrict__ cand, const float* __restrict__ cls_thresh,
               float* __restrict__ newth)
{
    int c = blockIdx.x;
    int t = threadIdx.x;
    unsigned mc = cand_cnt[c];
    int m = (int)(mc < (unsigned)CAND_MAX ? mc : (unsigned)CAND_MAX);
    int r = sel[2 * c + 1];
    int B = sel[2 * c];
    float lo = (float)B * (1.0f / 8192.0f);          // exact: B*2^-13

    __shared__ float    v[CAND_MAX];                  // 16 KB
    __shared__ unsigned h[SUBB];                      // 4 KB
    __shared__ unsigned sc[256];
    __shared__ float    w[WCAP];                      // 4 KB
    __shared__ unsigned wk;
    __shared__ int      selS, selR;
    __shared__ float    result;

    for (int i = t; i < SUBB; i += 256) h[i] = 0u;
    if (t == 0) wk = 0u;
    __syncthreads();

    for (int i = t; i < m; i += 256) {
        float x = cand[c * CAND_MAX + i];
        v[i] = x;
        int s = (int)((x - lo) * 8388608.0f);         // *2^23 -> [0,1024)
        s = s < 0 ? 0 : (s > SUBB - 1 ? SUBB - 1 : s);
        atomicAdd(&h[s], 1u);
    }
    __syncthreads();

    // descending scan: thread t owns sub-bins [SUBB-(t+1)*4, SUBB-t*4)
    int base = SUBB - (t + 1) * 4;
    unsigned s_ = h[base] + h[base + 1] + h[base + 2] + h[base + 3];
    sc[t] = s_;
    __syncthreads();
    for (int off = 1; off < 256; off <<= 1) {
        unsigned vt = sc[t];
        unsigned vp = (t >= off) ? sc[t - off] : 0u;
        __syncthreads();
        sc[t] = vt + vp;
        __syncthreads();
    }
    unsigned above = sc[t] - s_;
    if ((unsigned)r >= above && (unsigned)r < above + s_) {
        unsigned cum = above;
        for (int i = 3; i >= 0; --i) {
            unsigned hh = h[base + i];
            if ((unsigned)r < cum + hh) { selS = base + i; selR = (int)((unsigned)r - cum); break; }
            cum += hh;
        }
    }
    __syncthreads();

    int S = selS, rr = selR;
    for (int i = t; i < m; i += 256) {
        float x = v[i];
        int s = (int)((x - lo) * 8388608.0f);
        s = s < 0 ? 0 : (s > SUBB - 1 ? SUBB - 1 : s);
        if (s == S) {
            unsigned p = atomicAdd(&wk, 1u);
            if (p < WCAP) w[p] = x;
        }
    }
    __syncthreads();

    int k = (int)(wk < (unsigned)WCAP ? wk : (unsigned)WCAP);
    for (int i = t; i < k; i += 256) {
        float x = w[i];
        int g = 0, e = 0;
        for (int j = 0; j < k; ++j) {
            g += (w[j] > x);
            e += (w[j] == x);
        }
        if (g <= rr && rr < g + e) result = x;        // duplicates write same value
    }
    __syncthreads();
    if (t == 0) {
        float thr = cls_thresh[c];
        float nt = 0.9f * thr + 0.1f * result;
        if (nt >= 1.0f) nt = 0.999f;
        newth[c] = nt;
    }
}

// ---------------- K5: masked reduction (4 px/thread) + fused output write ----------------
__global__ __launch_bounds__(256)
void k5_reduce(const float4* __restrict__ conf, const float4* __restrict__ loss,
               const uchar4* __restrict__ label, const float* __restrict__ newth,
               float* __restrict__ accum, unsigned int* __restrict__ ticket,
               float* __restrict__ out)
{
    __shared__ float th[NCLS];
    if (threadIdx.x < NCLS) th[threadIdx.x] = newth[threadIdx.x];
    __syncthreads();

    int g = blockIdx.x * 256 + threadIdx.x;
    float4 c4 = conf[g];
    float4 s4 = loss[g];
    uchar4 l4 = label[g];
    float cf[4] = {c4.x, c4.y, c4.z, c4.w};
    float lv[4] = {s4.x, s4.y, s4.z, s4.w};
    int   lb[4] = {l4.x, l4.y, l4.z, l4.w};

    float ls = 0.0f; int mask = 0, solid = 0;
#pragma unroll
    for (int i = 0; i < 4; ++i) {
        bool m = cf[i] > th[lb[i]];
        mask  += m ? 1 : 0;
        solid += (cf[i] > 0.8f) ? 1 : 0;
        ls    += m ? fmaxf(lv[i], 1e-8f) : 0.0f;
    }

    for (int off = 32; off > 0; off >>= 1) {
        ls    += __shfl_down(ls, off, 64);
        mask  += __shfl_down(mask, off, 64);
        solid += __shfl_down(solid, off, 64);
    }
    __shared__ float s_ls[4];
    __shared__ int   s_m[4], s_s[4];
    int w = threadIdx.x >> 6;
    if ((threadIdx.x & 63) == 0) { s_ls[w] = ls; s_m[w] = mask; s_s[w] = solid; }
    __syncthreads();

    __shared__ unsigned done_rank;
    if (threadIdx.x == 0) {
        float L = s_ls[0] + s_ls[1] + s_ls[2] + s_ls[3];
        int   M = s_m[0] + s_m[1] + s_m[2] + s_m[3];
        int   S = s_s[0] + s_s[1] + s_s[2] + s_s[3];
        atomicAdd(&accum[0], L);
        atomicAdd(&((unsigned int*)accum)[1], (unsigned)M);
        atomicAdd(&((unsigned int*)accum)[2], (unsigned)S);
        __threadfence();
        done_rank = atomicAdd(ticket, 1u);
    }
    __syncthreads();
    if (done_rank == gridDim.x - 1 && threadIdx.x == 0) {   // last block writes outputs
        __threadfence();
        float    sum = atomicAdd(&accum[0], 0.0f);
        unsigned cm  = atomicAdd(&((unsigned int*)accum)[1], 0u);
        unsigned cs  = atomicAdd(&((unsigned int*)accum)[2], 0u);
        float den = fmaxf((float)cm, 1.0f);
        out[0] = sum / den;
        out[1] = (float)cm / (float)TPIX;
        out[2] = (float)cs / (float)TPIX;
    }
}

extern "C" void kernel_launch(void* const* d_in, const int* in_sizes, int n_in,
                              void* d_out, int out_size, void* d_ws, size_t ws_size,
                              hipStream_t stream)
{
    const float* lb  = (const float*)d_in[0];
    const float* la  = (const float*)d_in[1];
    const float* cth = (const float*)d_in[2];
    float* out = (float*)d_out;

    char* ws = (char*)d_ws;
    unsigned int* hist     = (unsigned int*)(ws + WS_HIST);
    unsigned int* cand_cnt = (unsigned int*)(ws + WS_CANDC);
    float*        accum    = (float*)(ws + WS_ACCUM);
    unsigned int* ticket   = (unsigned int*)(ws + WS_TICKET);
    int*          sel      = (int*)(ws + WS_SEL);
    float*        newth    = (float*)(ws + WS_NEWTH);
    float*        conf     = (float*)(ws + WS_CONF);
    float*        loss     = (float*)(ws + WS_LOSS);
    unsigned char* label   = (unsigned char*)(ws + WS_LABEL);
    float*        cand     = (float*)(ws + WS_CAND);

    hipMemsetAsync(ws, 0, WS_ZERO, stream);

    dim3 blk(256);
    dim3 grd4(TPIX / 4 / 256);           // 1024 blocks, 4 px/thread

    k1_pixel<<<grd4, blk, 0, stream>>>((const float4*)lb, (const float4*)la,
                                       (float4*)conf, (float4*)loss,
                                       (unsigned int*)label, hist);
    k2_select<<<NCLS, blk, 0, stream>>>(hist, cth, sel, cand_cnt, cand);
    k3_gather<<<grd4, blk, 0, stream>>>((const float4*)conf, (const uchar4*)label,
                                        sel, cand_cnt, cand);
    k4_thresh<<<NCLS, blk, 0, stream>>>(sel, cand_cnt, cand, cth, newth);
    k5_reduce<<<grd4, blk, 0, stream>>>((const float4*)conf, (const float4*)loss,
                                        (const uchar4*)label, newth, accum, ticket, out);
}